// Round 9
// baseline (283.534 us; speedup 1.0000x reference)
//
#include <hip/hip_runtime.h>

typedef unsigned int uint;
typedef unsigned short ushort;
typedef __attribute__((ext_vector_type(8))) short  short8;   // 8 bf16 (4 VGPRs)
typedef __attribute__((ext_vector_type(8))) unsigned short u16x8;
typedef __attribute__((ext_vector_type(4))) float  f32x4;    // MFMA accumulator

// round-to-nearest-even f32 -> bf16
__device__ __forceinline__ ushort f2b(float f) {
    uint u = __float_as_uint(f);
    u += 0x7FFFu + ((u >> 16) & 1u);
    return (ushort)(u >> 16);
}

__device__ __forceinline__ void async16(const void* g, void* l) {
    __builtin_amdgcn_global_load_lds(
        (const __attribute__((address_space(1))) void*)g,
        (__attribute__((address_space(3))) void*)l,
        16, 0, 0);
}

// ---------------------------------------------------------------------------
// Kernel 1: expand c (16,16,256) f32 -> Wt bf16 [N=4096][K=4096]
// ---------------------------------------------------------------------------
__global__ __launch_bounds__(256) void expand_w(const float* __restrict__ c,
                                                ushort* __restrict__ Wt) {
    const int j = blockIdx.x >> 4;
    const int i = blockIdx.x & 15;
    __shared__ ushort crev2[512];
    const float* cs = c + (size_t)(j * 16 + i) * 256;
    const int t = threadIdx.x;
    {
        ushort b = f2b(cs[(256 - t) & 255]);
        crev2[t] = b;
        crev2[t + 256] = b;
    }
    __syncthreads();
    const int tr = t >> 5;
    const int tm = (t & 31) * 8;
    for (int rb = 0; rb < 256; rb += 8) {
        const int k = rb + tr;
        u16x8 v;
#pragma unroll
        for (int u = 0; u < 8; ++u) v[u] = crev2[tm + u - k + 256];
        *(u16x8*)&Wt[(size_t)(j * 256 + k) * 4096 + i * 256 + tm] = v;
    }
}

// ---------------------------------------------------------------------------
// Kernel 2: x f32 -> bf16
// ---------------------------------------------------------------------------
__global__ __launch_bounds__(256) void conv_x(const float4* __restrict__ x,
                                              u16x8* __restrict__ xb, int n8) {
    int idx = blockIdx.x * blockDim.x + threadIdx.x;
    const int stride = gridDim.x * blockDim.x;
    for (; idx < n8; idx += stride) {
        float4 a = x[idx * 2];
        float4 b = x[idx * 2 + 1];
        u16x8 o;
        o[0] = f2b(a.x); o[1] = f2b(a.y); o[2] = f2b(a.z); o[3] = f2b(a.w);
        o[4] = f2b(b.x); o[5] = f2b(b.y); o[6] = f2b(b.z); o[7] = f2b(b.w);
        xb[idx] = o;
    }
}

// ---------------------------------------------------------------------------
// Kernel 3: 256x256 8-phase GEMM, ds_reads software-pipelined one phase ahead
//   C[8192][4096] = A[8192][4096] * Bt[4096][4096]^T + bias
// R9 delta vs R8: each quadrant's fragment reads issue one phase EARLY;
// waits are counted lgkmcnt(4) (not 0) so reads drain DURING the previous
// quadrant's MFMAs. Cross-tile B+af01 reads issue at PH4/PH8 after the
// vmcnt(6)+barrier that proves the buffer valid. Frag regs double-buffered
// with static names (afc/afn, bfc/bfn). Slot-overwrite safety: every read
// set completes (counted wait) before its phase's closing barrier; the
// overwriting STAGE issues after that barrier.
// ---------------------------------------------------------------------------
#define BAR()   __builtin_amdgcn_s_barrier()
#define LGKM0() asm volatile("s_waitcnt lgkmcnt(0)" ::: "memory")
#define LGKM4() asm volatile("s_waitcnt lgkmcnt(4)" ::: "memory")
#define VMC6()  asm volatile("s_waitcnt vmcnt(6)" ::: "memory")
#define VMC0()  asm volatile("s_waitcnt vmcnt(0)" ::: "memory")
#define PRIO1() __builtin_amdgcn_s_setprio(1)
#define PRIO0() __builtin_amdgcn_s_setprio(0)

__global__ __launch_bounds__(512, 2) void gemm256(const ushort* __restrict__ A,
                                                  const ushort* __restrict__ Bt,
                                                  const float* __restrict__ bias,
                                                  float* __restrict__ C) {
    constexpr int K = 4096, N = 4096;
    __shared__ __align__(16) ushort lds[65536];  // 128 KiB

    const int tid  = threadIdx.x;
    const int wave = tid >> 6;
    const int lane = tid & 63;
    const int wr   = wave >> 2;       // 0..1
    const int wc   = wave & 3;        // 0..3
    const int lrow = lane & 15;
    const int kgrp = lane >> 4;

    // T1: XCD 8x8-square swizzle
    const int wg  = (int)blockIdx.x;
    const int xcd = wg & 7;
    const int idx = wg >> 3;
    const int bm  = (xcd & 3) * 8 + (idx & 7);   // 32 M-tiles
    const int bn  = (xcd >> 2) * 8 + (idx >> 3); // 16 N-tiles

    // staging: linear LDS dest (gload_lds), inverse swizzle on global source
    const int r0  = tid >> 3;                              // 0..63
    const int cst = ((tid & 7) << 3) ^ ((r0 & 7) << 3);    // elem col, pre-swz
    const ushort* gA  = A  + (size_t)(bm * 256 + r0) * K + cst;
    const ushort* gB  = Bt + (size_t)(bn * 256 + r0) * K + cst;
    const ushort* gA2 = gA + (size_t)128 * K;
    const ushort* gB2 = gB + (size_t)128 * K;
    const size_t r64 = (size_t)64 * K;

#define STAGE(buf, slot, src, kt) do {                          \
        ushort* d_ = &lds[(buf) * 32768 + (slot) * 8192 + tid * 8]; \
        async16((src) + (kt), d_);                              \
        async16((src) + r64 + (kt), d_ + 4096);                 \
    } while (0)

    const int swz = (lrow & 7) << 3;   // 3-bit read swizzle (elems)

    f32x4 acc[8][4];
#pragma unroll
    for (int m = 0; m < 8; ++m)
#pragma unroll
        for (int n = 0; n < 4; ++n) acc[m][n] = (f32x4){0.f, 0.f, 0.f, 0.f};

    short8 afc[2][2], afn[2][2], bfc[4][2], bfn[4][2];

    // A fragments for m-frags {2qm, 2qm+1} (4 x ds_read_b128)
#define LDAQ(dst, base, qm) do {                                             \
        _Pragma("unroll")                                                    \
        for (int m_ = 0; m_ < 2; ++m_) {                                     \
            const int mf_ = 2 * (qm) + m_;                                   \
            _Pragma("unroll")                                                \
            for (int ks_ = 0; ks_ < 2; ++ks_)                                \
                dst[m_][ks_] = *(const short8*)&lds[(base) + wr * 8192 +     \
                    (mf_ >> 2) * 4096 + (mf_ & 3) * 1024 + lrow * 64 +       \
                    ((ks_ * 32 + kgrp * 8) ^ swz)];                          \
        }                                                                    \
    } while (0)

    // all 4 n fragments (8 x ds_read_b128)
#define LDBQ(dst, base) do {                                                 \
        _Pragma("unroll")                                                    \
        for (int n_ = 0; n_ < 4; ++n_)                                       \
            _Pragma("unroll")                                                \
            for (int ks_ = 0; ks_ < 2; ++ks_)                                \
                dst[n_][ks_] = *(const short8*)&lds[(base) +                 \
                    (2 + (wc >> 1)) * 8192 + (wc & 1) * 4096 +               \
                    n_ * 1024 + lrow * 64 +                                  \
                    ((ks_ * 32 + kgrp * 8) ^ swz)];                          \
    } while (0)

#define MMQ(QM, AF, BF) do {                                                 \
        _Pragma("unroll")                                                    \
        for (int m_ = 0; m_ < 2; ++m_)                                       \
            _Pragma("unroll")                                                \
            for (int n_ = 0; n_ < 4; ++n_)                                   \
                _Pragma("unroll")                                            \
                for (int ks_ = 0; ks_ < 2; ++ks_)                            \
                    acc[2 * (QM) + m_][n_] =                                 \
                        __builtin_amdgcn_mfma_f32_16x16x32_bf16(             \
                            AF[m_][ks_], BF[n_][ks_],                        \
                            acc[2 * (QM) + m_][n_], 0, 0, 0);                \
    } while (0)

    // prologue: tile0 (buf0) fully + tile1 (buf1) 3 of 4 halves
    STAGE(0, 2, gB, 0);  STAGE(0, 3, gB2, 0);  STAGE(0, 0, gA, 0);  STAGE(0, 1, gA2, 0);
    STAGE(1, 2, gB, 64); STAGE(1, 3, gB2, 64); STAGE(1, 0, gA, 64);
    VMC6();   // 14 issued, wait 8 oldest (= all of tile0)
    BAR();
    LDBQ(bfc, 0); LDAQ(afc, 0, 0);     // 12 ds_reads outstanding (tile0)

    for (int it = 0; it < 31; ++it) {
        const int kt2 = it * 128 + 128, kt3 = kt2 + 64, ktn = kt2 - 64;
        // ---- tile t (buf0) ----
        // PH1: prefetch a23; stage t+1's A1
        LDAQ(afn, 0, 1);
        STAGE(1, 1, gA2, ktn);
        BAR(); LGKM4(); PRIO1(); MMQ(0, afc, bfc); PRIO0(); BAR();
        // PH2: prefetch a45; stage t+2 B0 (bfc reads completed pre-PH1-close)
        LDAQ(afc, 0, 2);
        STAGE(0, 2, gB, kt2);
        BAR(); LGKM4(); PRIO1(); MMQ(1, afn, bfc); PRIO0(); BAR();
        // PH3: prefetch a67; stage t+2 B1
        LDAQ(afn, 0, 3);
        STAGE(0, 3, gB2, kt2);
        BAR(); LGKM4(); PRIO1(); MMQ(2, afc, bfc); PRIO0(); BAR();
        // PH4: stage t+2 A0; vmcnt(6) -> tile t+1 landed; prefetch its B+a01
        STAGE(0, 0, gA, kt2);
        VMC6();
        BAR(); LGKM0();
        LDBQ(bfn, 32768); LDAQ(afc, 32768, 0);
        PRIO1(); MMQ(3, afn, bfc); PRIO0(); BAR();
        // ---- tile t+1 (buf1) ----
        // PH5: prefetch a23; stage t+2 A1
        LDAQ(afn, 32768, 1);
        STAGE(0, 1, gA2, kt2);
        BAR(); LGKM4(); PRIO1(); MMQ(0, afc, bfn); PRIO0(); BAR();
        // PH6: prefetch a45; stage t+3 B0
        LDAQ(afc, 32768, 2);
        STAGE(1, 2, gB, kt3);
        BAR(); LGKM4(); PRIO1(); MMQ(1, afn, bfn); PRIO0(); BAR();
        // PH7: prefetch a67; stage t+3 B1
        LDAQ(afn, 32768, 3);
        STAGE(1, 3, gB2, kt3);
        BAR(); LGKM4(); PRIO1(); MMQ(2, afc, bfn); PRIO0(); BAR();
        // PH8: stage t+3 A0; vmcnt(6) -> tile t+2 landed; prefetch its B+a01
        STAGE(1, 0, gA, kt3);
        VMC6();
        BAR(); LGKM0();
        LDBQ(bfc, 0); LDAQ(afc, 0, 0);
        PRIO1(); MMQ(3, afn, bfn); PRIO0(); BAR();
    }

    // final: tiles 62 (buf0) and 63 (buf1); entering with bfc+afc(t62) issued
    {
        LDAQ(afn, 0, 1);
        STAGE(1, 1, gA2, 4032);          // last half of tile 63
        BAR(); LGKM4(); PRIO1(); MMQ(0, afc, bfc); PRIO0(); BAR();
        LDAQ(afc, 0, 2);
        BAR(); LGKM4(); PRIO1(); MMQ(1, afn, bfc); PRIO0(); BAR();
        LDAQ(afn, 0, 3);
        BAR(); LGKM4(); PRIO1(); MMQ(2, afc, bfc); PRIO0(); BAR();
        VMC0();                           // tile 63 fully landed
        BAR(); LGKM0();
        LDBQ(bfn, 32768); LDAQ(afc, 32768, 0);
        PRIO1(); MMQ(3, afn, bfc); PRIO0(); BAR();
        // tile 63: no pending LDS writes -> no barriers needed
        LDAQ(afn, 32768, 1);
        LGKM4(); PRIO1(); MMQ(0, afc, bfn); PRIO0();
        LDAQ(afc, 32768, 2);
        LGKM4(); PRIO1(); MMQ(1, afn, bfn); PRIO0();
        LDAQ(afn, 32768, 3);
        LGKM4(); PRIO1(); MMQ(2, afc, bfn); PRIO0();
        LGKM0(); PRIO1(); MMQ(3, afn, bfn); PRIO0();
    }

    // epilogue: D row = kgrp*4 + reg, col = lrow (verified m89 layout)
    const int colbase = bn * 256 + wc * 64 + lrow;
    float bv[4];
#pragma unroll
    for (int n = 0; n < 4; ++n) bv[n] = bias[colbase + n * 16];
    const int rowbase = bm * 256 + wr * 128 + kgrp * 4;
#pragma unroll
    for (int m = 0; m < 8; ++m)
#pragma unroll
        for (int n = 0; n < 4; ++n) {
            const size_t base = (size_t)(rowbase + m * 16) * N + colbase + n * 16;
#pragma unroll
            for (int r = 0; r < 4; ++r)
                C[base + (size_t)r * N] = acc[m][n][r] + bv[n];
        }
#undef STAGE
#undef LDAQ
#undef LDBQ
#undef MMQ
}

// ---------------------------------------------------------------------------
extern "C" void kernel_launch(void* const* d_in, const int* in_sizes, int n_in,
                              void* d_out, int out_size, void* d_ws, size_t ws_size,
                              hipStream_t stream) {
    const float* x    = (const float*)d_in[0];   // (4,2048,4096) f32
    const float* c    = (const float*)d_in[1];   // (16,16,256) f32
    const float* bias = (const float*)d_in[2];   // (4096,) f32
    float* out = (float*)d_out;                  // (4,2048,4096) f32

    ushort* Wb = (ushort*)d_ws;                  // 32 MiB
    ushort* Xb = Wb + (size_t)4096 * 4096;       // 64 MiB

    hipLaunchKernelGGL(expand_w, dim3(256), dim3(256), 0, stream, c, Wb);
    hipLaunchKernelGGL(conv_x, dim3(2048), dim3(256), 0, stream,
                       (const float4*)x, (u16x8*)Xb, 33554432 / 8);
    hipLaunchKernelGGL(gemm256, dim3(512), dim3(512), 0, stream,
                       Xb, Wb, bias, out);
}

// Round 10
// 268.825 us; speedup vs baseline: 1.0547x; 1.0547x over previous
//
#include <hip/hip_runtime.h>

typedef unsigned int uint;
typedef unsigned short ushort;
typedef __attribute__((ext_vector_type(8))) short  short8;   // 8 bf16 (4 VGPRs)
typedef __attribute__((ext_vector_type(8))) unsigned short u16x8;
typedef __attribute__((ext_vector_type(4))) float  f32x4;    // MFMA accumulator

// round-to-nearest-even f32 -> bf16
__device__ __forceinline__ ushort f2b(float f) {
    uint u = __float_as_uint(f);
    u += 0x7FFFu + ((u >> 16) & 1u);
    return (ushort)(u >> 16);
}

__device__ __forceinline__ void async16(const void* g, void* l) {
    __builtin_amdgcn_global_load_lds(
        (const __attribute__((address_space(1))) void*)g,
        (__attribute__((address_space(3))) void*)l,
        16, 0, 0);
}

// ---------------------------------------------------------------------------
// Kernel 1 (fused prep):
//  blocks 0..255:   expand c (16,16,256) f32 -> Wt bf16 [4096][4096]
//                   Wt[j*256+k][i*256+m] = c[j,i,(k-m)&255]
//  blocks 256..2303: x f32 -> bf16 (grid-stride over 4.2M u16x8 groups)
// ---------------------------------------------------------------------------
__global__ __launch_bounds__(256) void prep(const float* __restrict__ c,
                                            ushort* __restrict__ Wt,
                                            const float4* __restrict__ x,
                                            u16x8* __restrict__ xb, int n8) {
    const int t = threadIdx.x;
    if (blockIdx.x < 256) {
        const int j = blockIdx.x >> 4;
        const int i = blockIdx.x & 15;
        __shared__ ushort crev2[512];
        const float* cs = c + (size_t)(j * 16 + i) * 256;
        {
            ushort b = f2b(cs[(256 - t) & 255]);
            crev2[t] = b;
            crev2[t + 256] = b;
        }
        __syncthreads();
        const int tr = t >> 5;
        const int tm = (t & 31) * 8;
        for (int rb = 0; rb < 256; rb += 8) {
            const int k = rb + tr;
            u16x8 v;
#pragma unroll
            for (int u = 0; u < 8; ++u) v[u] = crev2[tm + u - k + 256];
            *(u16x8*)&Wt[(size_t)(j * 256 + k) * 4096 + i * 256 + tm] = v;
        }
    } else {
        int idx = (blockIdx.x - 256) * 256 + t;
        const int stride = (gridDim.x - 256) * 256;
        for (; idx < n8; idx += stride) {
            float4 a = x[idx * 2];
            float4 b = x[idx * 2 + 1];
            u16x8 o;
            o[0] = f2b(a.x); o[1] = f2b(a.y); o[2] = f2b(a.z); o[3] = f2b(a.w);
            o[4] = f2b(b.x); o[5] = f2b(b.y); o[6] = f2b(b.z); o[7] = f2b(b.w);
            xb[idx] = o;
        }
    }
}

// ---------------------------------------------------------------------------
// Kernel 2: 256x256-tile 8-phase GEMM (T1+T2+T3+T4+T5), even ds_read spread
//   C[8192][4096] = A[8192][4096] * Bt[4096][4096]^T + bias
// 512 thr = 8 waves (2M x 4N), per-wave 128x64. BK=64, 2 K-tiles/iter.
// LDS 128 KiB: 2 bufs x 4 slots(A0,A1,B0,B1) x [128][64] bf16.
// T2 swizzle (3-bit): 16B-slot s' = s ^ (row&7); inverse on GLOBAL source
// (linear gload_lds dest) + same XOR on ds_read col. 0-conflict (verified).
// ds_reads 12/4/4/4 per K-tile; m201's pre-barrier lgkmcnt(8) hint in the
// 12-read phases (PH1/PH5) so the post-barrier drain serves <=8.
// ---------------------------------------------------------------------------
#define BAR()   __builtin_amdgcn_s_barrier()
#define LGKM0() asm volatile("s_waitcnt lgkmcnt(0)" ::: "memory")
#define LGKM8() asm volatile("s_waitcnt lgkmcnt(8)" ::: "memory")
#define VMC6()  asm volatile("s_waitcnt vmcnt(6)" ::: "memory")
#define VMC0()  asm volatile("s_waitcnt vmcnt(0)" ::: "memory")
#define PRIO1() __builtin_amdgcn_s_setprio(1)
#define PRIO0() __builtin_amdgcn_s_setprio(0)

__global__ __launch_bounds__(512, 2) void gemm256(const ushort* __restrict__ A,
                                                  const ushort* __restrict__ Bt,
                                                  const float* __restrict__ bias,
                                                  float* __restrict__ C) {
    constexpr int K = 4096, N = 4096;
    __shared__ __align__(16) ushort lds[65536];  // 128 KiB

    const int tid  = threadIdx.x;
    const int wave = tid >> 6;
    const int lane = tid & 63;
    const int wr   = wave >> 2;       // 0..1
    const int wc   = wave & 3;        // 0..3
    const int lrow = lane & 15;
    const int kgrp = lane >> 4;

    // T1: XCD 8x8-square swizzle
    const int wg  = (int)blockIdx.x;
    const int xcd = wg & 7;
    const int idx = wg >> 3;
    const int bm  = (xcd & 3) * 8 + (idx & 7);   // 32 M-tiles
    const int bn  = (xcd >> 2) * 8 + (idx >> 3); // 16 N-tiles

    // staging: linear LDS dest (gload_lds), inverse swizzle on global source
    const int r0  = tid >> 3;                              // 0..63
    const int cst = ((tid & 7) << 3) ^ ((r0 & 7) << 3);    // elem col, pre-swz
    const ushort* gA  = A  + (size_t)(bm * 256 + r0) * K + cst;
    const ushort* gB  = Bt + (size_t)(bn * 256 + r0) * K + cst;
    const ushort* gA2 = gA + (size_t)128 * K;
    const ushort* gB2 = gB + (size_t)128 * K;
    const size_t r64 = (size_t)64 * K;

#define STAGE(buf, slot, src, kt) do {                          \
        ushort* d_ = &lds[(buf) * 32768 + (slot) * 8192 + tid * 8]; \
        async16((src) + (kt), d_);                              \
        async16((src) + r64 + (kt), d_ + 4096);                 \
    } while (0)

    const int swz = (lrow & 7) << 3;   // 3-bit read swizzle (elems)

    f32x4 acc[8][4];
#pragma unroll
    for (int m = 0; m < 8; ++m)
#pragma unroll
        for (int n = 0; n < 4; ++n) acc[m][n] = (f32x4){0.f, 0.f, 0.f, 0.f};

    short8 af[2][2], bf[4][2];

    // LDAq(base, qm): A fragments for m-frags {2qm, 2qm+1} (4 x ds_read_b128)
    auto LDAq = [&](int base, int qm) {
#pragma unroll
        for (int m = 0; m < 2; ++m) {
            const int mf = 2 * qm + m;
#pragma unroll
            for (int ks = 0; ks < 2; ++ks)
                af[m][ks] = *(const short8*)&lds[base + wr * 8192 +
                                                 (mf >> 2) * 4096 +
                                                 (mf & 3) * 1024 + lrow * 64 +
                                                 ((ks * 32 + kgrp * 8) ^ swz)];
        }
    };
    // LDB(base): all 4 n fragments (8 x ds_read_b128)
    auto LDB = [&](int base) {
#pragma unroll
        for (int n = 0; n < 4; ++n)
#pragma unroll
            for (int ks = 0; ks < 2; ++ks)
                bf[n][ks] = *(const short8*)&lds[base + (2 + (wc >> 1)) * 8192 +
                                                 (wc & 1) * 4096 +
                                                 n * 1024 + lrow * 64 +
                                                 ((ks * 32 + kgrp * 8) ^ swz)];
    };

#define MMQ(QM) do {                                                         \
        _Pragma("unroll")                                                    \
        for (int m_ = 0; m_ < 2; ++m_)                                       \
            _Pragma("unroll")                                                \
            for (int n_ = 0; n_ < 4; ++n_)                                   \
                _Pragma("unroll")                                            \
                for (int ks_ = 0; ks_ < 2; ++ks_)                            \
                    acc[2 * (QM) + m_][n_] =                                 \
                        __builtin_amdgcn_mfma_f32_16x16x32_bf16(             \
                            af[m_][ks_], bf[n_][ks_],                        \
                            acc[2 * (QM) + m_][n_], 0, 0, 0);                \
    } while (0)

    // prologue: tile0 (buf0) fully + tile1 (buf1) 3 of 4 halves
    STAGE(0, 2, gB, 0);  STAGE(0, 3, gB2, 0);  STAGE(0, 0, gA, 0);  STAGE(0, 1, gA2, 0);
    STAGE(1, 2, gB, 64); STAGE(1, 3, gB2, 64); STAGE(1, 0, gA, 64);
    VMC6();   // 14 issued, wait 8 oldest (= all of tile0)
    BAR();

    for (int it = 0; it < 31; ++it) {
        const int kt2 = it * 128 + 128, kt3 = kt2 + 64, ktn = kt2 - 64;
        // ---- tile t (buf0) ----
        // PH1: read B all + A m01 (12 reads); stage t+1's A1; pre-drain to 8
        LDB(0); LDAq(0, 0);
        STAGE(1, 1, gA2, ktn);
        LGKM8();
        BAR(); LGKM0(); PRIO1(); MMQ(0); PRIO0(); BAR();
        // PH2: read A m23; stage t+2 B0 (bf lives in regs)
        LDAq(0, 1);
        STAGE(0, 2, gB, kt2);
        BAR(); LGKM0(); PRIO1(); MMQ(1); PRIO0(); BAR();
        // PH3: read A m45; stage t+2 B1
        LDAq(0, 2);
        STAGE(0, 3, gB2, kt2);
        BAR(); LGKM0(); PRIO1(); MMQ(2); PRIO0(); BAR();
        // PH4: read A m67; stage t+2 A0; counted vmcnt -> tile t+1 landed
        LDAq(0, 3);
        STAGE(0, 0, gA, kt2);
        VMC6();
        BAR(); LGKM0(); PRIO1(); MMQ(3); PRIO0(); BAR();
        // ---- tile t+1 (buf1) ----
        // PH5: read B all + A m01; stage t+2 A1; pre-drain to 8
        LDB(32768); LDAq(32768, 0);
        STAGE(0, 1, gA2, kt2);
        LGKM8();
        BAR(); LGKM0(); PRIO1(); MMQ(0); PRIO0(); BAR();
        // PH6: read A m23; stage t+3 B0
        LDAq(32768, 1);
        STAGE(1, 2, gB, kt3);
        BAR(); LGKM0(); PRIO1(); MMQ(1); PRIO0(); BAR();
        // PH7: read A m45; stage t+3 B1
        LDAq(32768, 2);
        STAGE(1, 3, gB2, kt3);
        BAR(); LGKM0(); PRIO1(); MMQ(2); PRIO0(); BAR();
        // PH8: read A m67; stage t+3 A0; counted vmcnt -> tile t+2 landed
        LDAq(32768, 3);
        STAGE(1, 0, gA, kt3);
        VMC6();
        BAR(); LGKM0(); PRIO1(); MMQ(3); PRIO0(); BAR();
    }

    // final iteration: tiles 62 (buf0, kt=3968) and 63 (buf1, kt=4032)
    {
        LDB(0); LDAq(0, 0);
        STAGE(1, 1, gA2, 4032);      // last half of tile 63
        LGKM8();
        BAR(); LGKM0(); PRIO1(); MMQ(0); PRIO0(); BAR();
        LDAq(0, 1);
        BAR(); LGKM0(); PRIO1(); MMQ(1); PRIO0(); BAR();
        LDAq(0, 2);
        BAR(); LGKM0(); PRIO1(); MMQ(2); PRIO0(); BAR();
        LDAq(0, 3);
        VMC0();                       // drain: tile 63 fully landed
        BAR(); LGKM0(); PRIO1(); MMQ(3); PRIO0(); BAR();
        // tile 63 (buf1): registers only, per-wave ordering suffices
        LDB(32768); LDAq(32768, 0);
        LGKM0(); PRIO1(); MMQ(0); PRIO0();
        LDAq(32768, 1);
        LGKM0(); PRIO1(); MMQ(1); PRIO0();
        LDAq(32768, 2);
        LGKM0(); PRIO1(); MMQ(2); PRIO0();
        LDAq(32768, 3);
        LGKM0(); PRIO1(); MMQ(3); PRIO0();
    }

    // epilogue: D row = kgrp*4 + reg, col = lrow (verified m89 layout)
    const int colbase = bn * 256 + wc * 64 + lrow;
    float bv[4];
#pragma unroll
    for (int n = 0; n < 4; ++n) bv[n] = bias[colbase + n * 16];
    const int rowbase = bm * 256 + wr * 128 + kgrp * 4;
#pragma unroll
    for (int m = 0; m < 8; ++m)
#pragma unroll
        for (int n = 0; n < 4; ++n) {
            const size_t base = (size_t)(rowbase + m * 16) * N + colbase + n * 16;
#pragma unroll
            for (int r = 0; r < 4; ++r)
                C[base + (size_t)r * N] = acc[m][n][r] + bv[n];
        }
#undef STAGE
#undef MMQ
}

// ---------------------------------------------------------------------------
extern "C" void kernel_launch(void* const* d_in, const int* in_sizes, int n_in,
                              void* d_out, int out_size, void* d_ws, size_t ws_size,
                              hipStream_t stream) {
    const float* x    = (const float*)d_in[0];   // (4,2048,4096) f32
    const float* c    = (const float*)d_in[1];   // (16,16,256) f32
    const float* bias = (const float*)d_in[2];   // (4096,) f32
    float* out = (float*)d_out;                  // (4,2048,4096) f32

    ushort* Wb = (ushort*)d_ws;                  // 32 MiB
    ushort* Xb = Wb + (size_t)4096 * 4096;       // 64 MiB

    hipLaunchKernelGGL(prep, dim3(2304), dim3(256), 0, stream,
                       c, Wb, (const float4*)x, (u16x8*)Xb, 33554432 / 8);
    hipLaunchKernelGGL(gemm256, dim3(512), dim3(512), 0, stream,
                       Xb, Wb, bias, out);
}